// Round 18
// baseline (171.364 us; speedup 1.0000x reference)
//
#include <hip/hip_runtime.h>
#include <math.h>
#include <stdint.h>

typedef __attribute__((ext_vector_type(8))) short short8;
typedef __attribute__((ext_vector_type(4))) float f32x4;

#define AS1 __attribute__((address_space(1)))
#define AS3 __attribute__((address_space(3)))

// async global->LDS DMA: 64 lanes x 16 B = 1 KB. LDS dest = uniform base +
// lane*16 (linear); global src is per-lane. Size must be literal 16.
__device__ __forceinline__ void dma1kb(const uint16_t* g, uint16_t* l) {
  __builtin_amdgcn_global_load_lds((const AS1 uint32_t*)g, (AS3 uint32_t*)l,
                                   16, 0, 0);
}

__device__ __forceinline__ uint32_t cvt_pk_bf16(float lo, float hi) {
  uint32_t r;
  asm("v_cvt_pk_bf16_f32 %0, %1, %2" : "=v"(r) : "v"(lo), "v"(hi));
  return r;
}

// inverse-distance weight; invalid j has cx=cy=1e30 -> d2 overflows to inf
// -> rcp(inf)=0, so invalid columns contribute exactly 0.
__device__ __forceinline__ float wfun(float hx, float hy, float cx, float cy) {
  float dx = hx - cx, dy = hy - cy;
  float d = __builtin_amdgcn_sqrtf(fmaf(dx, dx, dy * dy));
  return __builtin_amdgcn_rcpf(d + 1e-4f);
}

// ---------------------------------------------------------------------------
// Kernel 1: hp = tanh(batch@W_h + b_h); hx,hy,validf,cxy per row. (verified)
__global__ __launch_bounds__(256) void k_head(
    const float* __restrict__ batch, const float* __restrict__ xywh,
    const float* __restrict__ W_h, const float* __restrict__ b_h,
    float* __restrict__ hp_out, float* __restrict__ hx, float* __restrict__ hy,
    float* __restrict__ validf, float2* __restrict__ cxy, int S, int F) {
  int wid = threadIdx.x >> 6;
  int lane = threadIdx.x & 63;
  int row = blockIdx.x * 4 + wid;
  if (row >= S) return;
  const float4* brow = (const float4*)(batch + (size_t)row * F);
  const float4* wh4 = (const float4*)W_h;  // W_h is [F,2] row-major
  int nf4 = F >> 2;
  float acc0 = 0.f, acc1 = 0.f;
  for (int k4 = lane; k4 < nf4; k4 += 64) {
    float4 b = brow[k4];
    float4 wa = wh4[2 * k4];
    float4 wb = wh4[2 * k4 + 1];
    acc0 += b.x * wa.x + b.y * wa.z + b.z * wb.x + b.w * wb.z;
    acc1 += b.x * wa.y + b.y * wa.w + b.z * wb.y + b.w * wb.w;
  }
  #pragma unroll
  for (int off = 32; off; off >>= 1) {
    acc0 += __shfl_xor(acc0, off, 64);
    acc1 += __shfl_xor(acc1, off, 64);
  }
  if (lane == 0) {
    float hp0 = tanhf(acc0 + b_h[0]);
    float hp1 = tanhf(acc1 + b_h[1]);
    float4 xy = ((const float4*)xywh)[row];
    hp_out[2 * row] = hp0;
    hp_out[2 * row + 1] = hp1;
    hx[row] = hp0 * xy.z * 4.0f + xy.x;  // SIGMA_X = 4
    hy[row] = hp1 * xy.w * 1.0f + xy.y;  // SIGMA_Y = 1
    bool v = (xy.x + xy.y + xy.z + xy.w >= 1e-8f);
    validf[row] = v ? 1.0f : 0.0f;
    cxy[row] = v ? make_float2(xy.x, xy.y) : make_float2(1e30f, 1e30f);
  }
}

// ---------------------------------------------------------------------------
// Kernel 1b: WgT[a][k] = bf16(Wg[k][a])  (verified)
__global__ __launch_bounds__(256) void k_prep_w(
    const float* __restrict__ Wg, uint16_t* __restrict__ WgT, int F, int A) {
  int idx = blockIdx.x * 256 + threadIdx.x;
  int a = idx % A;
  int k0 = (idx / A) * 8;
  if (k0 >= F) return;
  float f[8];
  #pragma unroll
  for (int e = 0; e < 8; ++e) f[e] = Wg[(size_t)(k0 + e) * A + a];
  uint4 v;
  v.x = cvt_pk_bf16(f[0], f[1]);
  v.y = cvt_pk_bf16(f[2], f[3]);
  v.z = cvt_pk_bf16(f[4], f[5]);
  v.w = cvt_pk_bf16(f[6], f[7]);
  *(uint4*)(WgT + (size_t)a * F + k0) = v;
}

// ---------------------------------------------------------------------------
// Kernel 2: targets via bf16 MFMA; tiled output tgt2[jb][a][jj].
// Round-16 verified version (full 256 cols/block, batch read once).
__global__ __launch_bounds__(256) void k_targets_mfma(
    const float* __restrict__ batch, const uint16_t* __restrict__ WgT,
    const float* __restrict__ bg, uint16_t* __restrict__ tgt2,
    int S, int F, int A) {
  int t = threadIdx.x;
  int lane = t & 63, wid = t >> 6;
  int wm = wid >> 1, wn = wid & 1;
  int i0 = blockIdx.x * 32;
  int row = i0 + wm * 16 + (lane & 15);
  int kch = lane >> 4;
  const float* ab = batch + (size_t)row * F + kch * 8;
  int ncol0 = wn * 128 + (lane & 15);
  const uint16_t* bb = WgT + (size_t)ncol0 * F + kch * 8;

  f32x4 acc[8] = {};
  float4 a0 = *(const float4*)(ab);
  float4 a1 = *(const float4*)(ab + 4);
  short8 bf[8];
  #pragma unroll
  for (int nf = 0; nf < 8; ++nf)
    bf[nf] = *(const short8*)(bb + (size_t)nf * 16 * F);

  for (int k0 = 0; k0 < F; k0 += 32) {
    int kn = (k0 + 32 < F) ? k0 + 32 : 0;  // wrap prefetch (harmless)
    float4 na0 = *(const float4*)(ab + kn);
    float4 na1 = *(const float4*)(ab + kn + 4);
    short8 nbf[8];
    #pragma unroll
    for (int nf = 0; nf < 8; ++nf)
      nbf[nf] = *(const short8*)(bb + kn + (size_t)nf * 16 * F);
    union { short8 s; uint32_t u[4]; } af;
    af.u[0] = cvt_pk_bf16(a0.x, a0.y);
    af.u[1] = cvt_pk_bf16(a0.z, a0.w);
    af.u[2] = cvt_pk_bf16(a1.x, a1.y);
    af.u[3] = cvt_pk_bf16(a1.z, a1.w);
    #pragma unroll
    for (int nf = 0; nf < 8; ++nf)
      acc[nf] = __builtin_amdgcn_mfma_f32_16x16x32_bf16(af.s, bf[nf], acc[nf], 0, 0, 0);
    a0 = na0; a1 = na1;
    #pragma unroll
    for (int nf = 0; nf < 8; ++nf) bf[nf] = nbf[nf];
  }

  int jb = blockIdx.x;
  int rloc = wm * 16 + (lane >> 4) * 4;   // row within tile, mult of 4
  #pragma unroll
  for (int nf = 0; nf < 8; ++nf) {
    int col = ncol0 + nf * 16;
    float b = bg[col];
    float o0 = fmaxf(acc[nf][0] + b, 0.f);
    float o1 = fmaxf(acc[nf][1] + b, 0.f);
    float o2 = fmaxf(acc[nf][2] + b, 0.f);
    float o3 = fmaxf(acc[nf][3] + b, 0.f);
    uint2 pk;
    pk.x = cvt_pk_bf16(o0, o1);
    pk.y = cvt_pk_bf16(o2, o3);
    *(uint2*)(tgt2 + ((size_t)jb * A + col) * 32 + rloc) = pk;
  }
}

// ---------------------------------------------------------------------------
// Kernel 3: out = rownorm(W) @ targets. Round-16 verified kernel (102.5 us)
// with ONE change: B staging via async global_load_lds DMA (linear unpadded
// Bt[2][2][256][32], 1-KB chunks, 2 DMA issues per wave per step) instead of
// 32 reg-staged ds_write_b128. Compiler's vmcnt(0)-before-barrier covers the
// DMA completion. Af scheme / c-prefetch / epilogue byte-identical to v16.
__global__ __launch_bounds__(1024, 4) void k_gather_v18(
    const uint16_t* __restrict__ tgt2, const float2* __restrict__ cxy,
    const float* __restrict__ hx, const float* __restrict__ hy,
    const float* __restrict__ validf, float* __restrict__ out, int S, int A) {
  __shared__ uint16_t Bt[2][2][256][32];   // [dbuf][kg][col][32hw]  64 KB
  __shared__ uint32_t Af[2][2][2][64][4];  // [dbuf][kg][wm][lane][s] 8 KB
  __shared__ float comb[32][260];          // kg=1 partial acc       33.3 KB
  __shared__ float rs_l[2][32][16];        // [kg][row][jp]           4 KB
  __shared__ float scale_s[32];

  int t = threadIdx.x;
  int lane = t & 63, wid = t >> 6;
  int kg = wid >> 3;                 // 0..1 (j-half)
  int sub = wid & 7;
  int wm = sub >> 2, wn = sub & 3;   // 2M x 4N
  int i0 = blockIdx.x * 32;
  int kch = lane >> 4;
  int n0 = wn * 64 + (lane & 15);    // col 0..255
  int NT = (S >> 1) / 32;            // 128 tiles per K-group
  const size_t TSTRIDE = (size_t)A * 32;

  // ---- writer role (all 1024 threads): (row wr, j-pair wjp) of kg's tile
  int u = t & 511;
  int wr = u & 31;                   // 0..31
  int wjp = u >> 5;                  // 0..15
  float hx_w = hx[i0 + wr], hy_w = hy[i0 + wr];
  uint32_t* afw0 = &Af[0][kg][wr >> 4][(wr & 15) | ((wjp >> 2) << 4)][wjp & 3];
  uint32_t* afw1 = &Af[1][kg][wr >> 4][(wr & 15) | ((wjp >> 2) << 4)][wjp & 3];
  const float2* gC = cxy + (size_t)kg * (S >> 1) + 2 * wjp;  // + tile*32

  // ---- DMA staging role: wave stages 2 x 1-KB chunks of its kg's tile.
  // chunk ck covers cols [ck*16, ck*16+16); lane l writes col ck*16+(l>>2),
  // quarter l&3  ->  global elem offset = ck*512 + l*8 (contiguous 1 KB).
  int ck0 = sub * 2;                 // 0,2,..,14
  const uint16_t* gB = tgt2 + (size_t)(kg * NT) * TSTRIDE
                       + (size_t)ck0 * 512 + lane * 8;

  f32x4 acc[4] = {};
  float rs = 0.f;

  // ---- prologue: DMA tile 0 into buffer 0; w(tile0) -> Af[0]
  {
    dma1kb(gB,       &Bt[0][kg][ck0 * 16][0]);
    dma1kb(gB + 512, &Bt[0][kg][(ck0 + 1) * 16][0]);
    float4 c0 = *(const float4*)(gC);
    float wA = wfun(hx_w, hy_w, c0.x, c0.y);
    float wB = wfun(hx_w, hy_w, c0.z, c0.w);
    rs += wA + wB;
    *afw0 = cvt_pk_bf16(wA, wB);
  }
  __syncthreads();
  float4 ccur = *(const float4*)(gC + 32);   // c for tile 1

  for (int ts = 0; ts < NT; ++ts) {
    int cur = ts & 1, nxt = cur ^ 1;
    int tn = (ts + 1 < NT) ? ts + 1 : 0;     // next tile (wrap harmless)
    int tf = (ts + 2 < NT) ? ts + 2 : 0;     // c two ahead

    // issue next-tile DMAs into Bt[nxt] (reads of nxt finished last iter)
    const uint16_t* bp = gB + (size_t)tn * TSTRIDE;
    dma1kb(bp,       &Bt[nxt][kg][ck0 * 16][0]);
    dma1kb(bp + 512, &Bt[nxt][kg][(ck0 + 1) * 16][0]);
    float4 cfut = *(const float4*)(gC + (size_t)tf * 32);

    // read A-frag + B-frags for current tile
    const uint32_t* afp = &Af[cur][kg][wm][lane][0];
    short8 afr = *(const short8*)afp;
    const uint16_t* br = &Bt[cur][kg][n0][kch * 8];
    short8 b0 = *(const short8*)(br);
    short8 b1 = *(const short8*)(br + 16 * 32);
    short8 b2 = *(const short8*)(br + 32 * 32);
    short8 b3 = *(const short8*)(br + 48 * 32);

    acc[0] = __builtin_amdgcn_mfma_f32_16x16x32_bf16(afr, b0, acc[0], 0, 0, 0);
    acc[1] = __builtin_amdgcn_mfma_f32_16x16x32_bf16(afr, b1, acc[1], 0, 0, 0);
    acc[2] = __builtin_amdgcn_mfma_f32_16x16x32_bf16(afr, b2, acc[2], 0, 0, 0);
    acc[3] = __builtin_amdgcn_mfma_f32_16x16x32_bf16(afr, b3, acc[3], 0, 0, 0);

    // w-gen for tile ts+1 (rs gated off on the wrapped last step)
    float wA = wfun(hx_w, hy_w, ccur.x, ccur.y);
    float wB = wfun(hx_w, hy_w, ccur.z, ccur.w);
    float g = (ts + 1 < NT) ? 1.f : 0.f;
    rs = fmaf(g, wA + wB, rs);
    uint32_t pk = cvt_pk_bf16(wA, wB);
    uint32_t* afw = nxt ? afw1 : afw0;
    *afw = pk;

    ccur = cfut;
    __syncthreads();   // compiler drains vmcnt (DMAs) + lgkm before barrier
  }

  // ---- rowsum: per-thread (kg,row,jp) partials -> LDS reduce
  rs_l[kg][wr][wjp] = rs;

  // kg=1 publishes its partial acc
  if (kg == 1) {
    int mre = wm * 16 + (lane >> 4) * 4;
    #pragma unroll
    for (int r = 0; r < 4; ++r) {
      comb[mre + r][n0]      = acc[0][r];
      comb[mre + r][n0 + 16] = acc[1][r];
      comb[mre + r][n0 + 32] = acc[2][r];
      comb[mre + r][n0 + 48] = acc[3][r];
    }
  }
  __syncthreads();
  if (t < 32) {
    float r = 0.f;
    #pragma unroll
    for (int jp = 0; jp < 16; ++jp) r += rs_l[0][t][jp] + rs_l[1][t][jp];
    float v = validf[i0 + t];
    scale_s[t] = (v > 0.f) ? 1.0f / fmaxf(r, 1e-30f) : 0.f;
  }
  __syncthreads();
  if (kg == 0) {
    int mre = wm * 16 + (lane >> 4) * 4;
    #pragma unroll
    for (int r = 0; r < 4; ++r) {
      float s = scale_s[mre + r];
      size_t base = (size_t)(i0 + mre + r) * A;
      out[base + n0]      = (acc[0][r] + comb[mre + r][n0]) * s;
      out[base + n0 + 16] = (acc[1][r] + comb[mre + r][n0 + 16]) * s;
      out[base + n0 + 32] = (acc[2][r] + comb[mre + r][n0 + 32]) * s;
      out[base + n0 + 48] = (acc[3][r] + comb[mre + r][n0 + 48]) * s;
    }
  }
}

extern "C" void kernel_launch(void* const* d_in, const int* in_sizes, int n_in,
                              void* d_out, int out_size, void* d_ws, size_t ws_size,
                              hipStream_t stream) {
  // inputs: 0 batch[S,F] 1 xywh[S,4] 2 OW 3 OH 4 actor_weights[S] 5 avg_pos[S,2]
  //         6 W_h[F,2] 7 b_h[2] 8 W_g[F,A] 9 b_g[A] 10 num_person
  const float* batch = (const float*)d_in[0];
  const float* xywh  = (const float*)d_in[1];
  const float* W_h   = (const float*)d_in[6];
  const float* b_h   = (const float*)d_in[7];
  const float* W_g   = (const float*)d_in[8];
  const float* b_g   = (const float*)d_in[9];
  int S = in_sizes[4];
  int F = in_sizes[0] / S;
  int A = in_sizes[9];

  float* out    = (float*)d_out;
  float* out_tw = out;                        // [S,A]
  float* out_hp = out + (size_t)S * A;        // [S,2]

  // workspace: tgt2 bf16 [S/32][A][32], WgT bf16 [A][F], hx/hy/validf, cxy
  uint16_t* tgt2 = (uint16_t*)d_ws;
  uint16_t* WgT  = tgt2 + (size_t)A * S;
  float* hxv = (float*)(WgT + (size_t)A * F);
  float* hyv = hxv + S;
  float* vfv = hyv + S;
  float2* cxyv = (float2*)(vfv + S);

  k_head<<<dim3((S + 3) / 4), 256, 0, stream>>>(batch, xywh, W_h, b_h,
                                                out_hp, hxv, hyv, vfv, cxyv, S, F);
  k_prep_w<<<dim3((A * F / 8 + 255) / 256), 256, 0, stream>>>(W_g, WgT, F, A);
  k_targets_mfma<<<dim3(S / 32), 256, 0, stream>>>(batch, WgT, b_g, tgt2, S, F, A);
  k_gather_v18<<<dim3(S / 32), 1024, 0, stream>>>(tgt2, cxyv, hxv, hyv, vfv,
                                                  out_tw, S, A);
}

// Round 19
// 160.874 us; speedup vs baseline: 1.0652x; 1.0652x over previous
//
#include <hip/hip_runtime.h>
#include <math.h>
#include <stdint.h>

typedef __attribute__((ext_vector_type(8))) short short8;
typedef __attribute__((ext_vector_type(4))) float f32x4;

__device__ __forceinline__ uint32_t cvt_pk_bf16(float lo, float hi) {
  uint32_t r;
  asm("v_cvt_pk_bf16_f32 %0, %1, %2" : "=v"(r) : "v"(lo), "v"(hi));
  return r;
}

// inverse-distance weight; invalid j has cx=cy=1e30 -> d2 overflows to inf
// -> rcp(inf)=0, so invalid columns contribute exactly 0.
__device__ __forceinline__ float wfun(float hx, float hy, float cx, float cy) {
  float dx = hx - cx, dy = hy - cy;
  float d = __builtin_amdgcn_sqrtf(fmaf(dx, dx, dy * dy));
  return __builtin_amdgcn_rcpf(d + 1e-4f);
}

// ---------------------------------------------------------------------------
// Kernel 1: hp = tanh(batch@W_h + b_h); hx,hy,validf,cxy per row. (verified)
__global__ __launch_bounds__(256) void k_head(
    const float* __restrict__ batch, const float* __restrict__ xywh,
    const float* __restrict__ W_h, const float* __restrict__ b_h,
    float* __restrict__ hp_out, float* __restrict__ hx, float* __restrict__ hy,
    float* __restrict__ validf, float2* __restrict__ cxy, int S, int F) {
  int wid = threadIdx.x >> 6;
  int lane = threadIdx.x & 63;
  int row = blockIdx.x * 4 + wid;
  if (row >= S) return;
  const float4* brow = (const float4*)(batch + (size_t)row * F);
  const float4* wh4 = (const float4*)W_h;  // W_h is [F,2] row-major
  int nf4 = F >> 2;
  float acc0 = 0.f, acc1 = 0.f;
  for (int k4 = lane; k4 < nf4; k4 += 64) {
    float4 b = brow[k4];
    float4 wa = wh4[2 * k4];
    float4 wb = wh4[2 * k4 + 1];
    acc0 += b.x * wa.x + b.y * wa.z + b.z * wb.x + b.w * wb.z;
    acc1 += b.x * wa.y + b.y * wa.w + b.z * wb.y + b.w * wb.w;
  }
  #pragma unroll
  for (int off = 32; off; off >>= 1) {
    acc0 += __shfl_xor(acc0, off, 64);
    acc1 += __shfl_xor(acc1, off, 64);
  }
  if (lane == 0) {
    float hp0 = tanhf(acc0 + b_h[0]);
    float hp1 = tanhf(acc1 + b_h[1]);
    float4 xy = ((const float4*)xywh)[row];
    hp_out[2 * row] = hp0;
    hp_out[2 * row + 1] = hp1;
    hx[row] = hp0 * xy.z * 4.0f + xy.x;  // SIGMA_X = 4
    hy[row] = hp1 * xy.w * 1.0f + xy.y;  // SIGMA_Y = 1
    bool v = (xy.x + xy.y + xy.z + xy.w >= 1e-8f);
    validf[row] = v ? 1.0f : 0.0f;
    cxy[row] = v ? make_float2(xy.x, xy.y) : make_float2(1e30f, 1e30f);
  }
}

// ---------------------------------------------------------------------------
// Kernel 1b: WgT[a][k] = bf16(Wg[k][a])  (verified)
__global__ __launch_bounds__(256) void k_prep_w(
    const float* __restrict__ Wg, uint16_t* __restrict__ WgT, int F, int A) {
  int idx = blockIdx.x * 256 + threadIdx.x;
  int a = idx % A;
  int k0 = (idx / A) * 8;
  if (k0 >= F) return;
  float f[8];
  #pragma unroll
  for (int e = 0; e < 8; ++e) f[e] = Wg[(size_t)(k0 + e) * A + a];
  uint4 v;
  v.x = cvt_pk_bf16(f[0], f[1]);
  v.y = cvt_pk_bf16(f[2], f[3]);
  v.z = cvt_pk_bf16(f[4], f[5]);
  v.w = cvt_pk_bf16(f[6], f[7]);
  *(uint4*)(WgT + (size_t)a * F + k0) = v;
}

// ---------------------------------------------------------------------------
// Kernel 2: targets via bf16 MFMA; tiled output tgt2[jb][a][jj]. (verified)
__global__ __launch_bounds__(256) void k_targets_mfma(
    const float* __restrict__ batch, const uint16_t* __restrict__ WgT,
    const float* __restrict__ bg, uint16_t* __restrict__ tgt2,
    int S, int F, int A) {
  int t = threadIdx.x;
  int lane = t & 63, wid = t >> 6;
  int wm = wid >> 1, wn = wid & 1;
  int i0 = blockIdx.x * 32;
  int row = i0 + wm * 16 + (lane & 15);
  int kch = lane >> 4;
  const float* ab = batch + (size_t)row * F + kch * 8;
  int ncol0 = wn * 128 + (lane & 15);
  const uint16_t* bb = WgT + (size_t)ncol0 * F + kch * 8;

  f32x4 acc[8] = {};
  float4 a0 = *(const float4*)(ab);
  float4 a1 = *(const float4*)(ab + 4);
  short8 bf[8];
  #pragma unroll
  for (int nf = 0; nf < 8; ++nf)
    bf[nf] = *(const short8*)(bb + (size_t)nf * 16 * F);

  for (int k0 = 0; k0 < F; k0 += 32) {
    int kn = (k0 + 32 < F) ? k0 + 32 : 0;  // wrap prefetch (harmless)
    float4 na0 = *(const float4*)(ab + kn);
    float4 na1 = *(const float4*)(ab + kn + 4);
    short8 nbf[8];
    #pragma unroll
    for (int nf = 0; nf < 8; ++nf)
      nbf[nf] = *(const short8*)(bb + kn + (size_t)nf * 16 * F);
    union { short8 s; uint32_t u[4]; } af;
    af.u[0] = cvt_pk_bf16(a0.x, a0.y);
    af.u[1] = cvt_pk_bf16(a0.z, a0.w);
    af.u[2] = cvt_pk_bf16(a1.x, a1.y);
    af.u[3] = cvt_pk_bf16(a1.z, a1.w);
    #pragma unroll
    for (int nf = 0; nf < 8; ++nf)
      acc[nf] = __builtin_amdgcn_mfma_f32_16x16x32_bf16(af.s, bf[nf], acc[nf], 0, 0, 0);
    a0 = na0; a1 = na1;
    #pragma unroll
    for (int nf = 0; nf < 8; ++nf) bf[nf] = nbf[nf];
  }

  int jb = blockIdx.x;
  int rloc = wm * 16 + (lane >> 4) * 4;   // row within tile, mult of 4
  #pragma unroll
  for (int nf = 0; nf < 8; ++nf) {
    int col = ncol0 + nf * 16;
    float b = bg[col];
    float o0 = fmaxf(acc[nf][0] + b, 0.f);
    float o1 = fmaxf(acc[nf][1] + b, 0.f);
    float o2 = fmaxf(acc[nf][2] + b, 0.f);
    float o3 = fmaxf(acc[nf][3] + b, 0.f);
    uint2 pk;
    pk.x = cvt_pk_bf16(o0, o1);
    pk.y = cvt_pk_bf16(o2, o3);
    *(uint2*)(tgt2 + ((size_t)jb * A + col) * 32 + rloc) = pk;
  }
}

// ---------------------------------------------------------------------------
// Kernel 3: out = rownorm(W) @ targets. v16's verified 1-barrier dbuf
// pipeline + v17's verified 2-rowgroup MFMA / wjp8 Af-production /
// full-column staging, at 512 threads = 8 waves = 2(kg) x 4(wn).
// Per interval (2 tiles): 8x6 LDS reads + 32 staging-writes + 16 Af-writes
// = 48 LDS instrs/tile (v16: 64). Stride-40 Bt (16B-aligned b128 — the
// stride-36 misalignment was the v9/v11/v12/v14 killer).
__global__ __launch_bounds__(512, 2) void k_gather_v19(
    const uint16_t* __restrict__ tgt2, const float2* __restrict__ cxy,
    const float* __restrict__ hx, const float* __restrict__ hy,
    const float* __restrict__ validf, float* __restrict__ out, int S, int A) {
  __shared__ uint16_t Bt[2][2][256][40];   // [dbuf][kg][col][40hw]  80 KB
  __shared__ uint32_t Af[2][2][2][64][4];  // [dbuf][kg][rg][lane][s] 16 KB
  __shared__ float comb[32][260];          // kg=1 partial acc       33.3 KB
  __shared__ float rs_l[2][32][8];         // [kg][row][wjp8]         2 KB
  __shared__ float scale_s[32];

  int t = threadIdx.x;               // 0..511
  int lane = t & 63, wid = t >> 6;   // 8 waves
  int kg = wid >> 2;                 // 0..1 (j-half)
  int wn = wid & 3;                  // 0..3 (64-col group)
  int i0 = blockIdx.x * 32;
  int kch = lane >> 4;
  int n0 = wn * 64 + (lane & 15);    // col 0..255
  int NT = (S >> 1) / 32;            // 128 tiles per K-group
  const size_t TSTRIDE = (size_t)A * 32;
  const int COLS = 40;

  // ---- writer role: (kg wkg, row wr, jp-base wjp8) -> 4 wfun/step
  // (v17-verified mapping: jp=wjp8 -> lane L0 slot sl; jp=wjp8+8 -> L1 sl)
  int wkg = t >> 8;
  int v = t & 255;
  int wr = v & 31;
  int wjp8 = v >> 5;                 // 0..7
  float hx_w = hx[i0 + wr], hy_w = hy[i0 + wr];
  int rgw = wr >> 4;
  int L0 = (wr & 15) | ((wjp8 >> 2) << 4);
  int L1 = (wr & 15) | (((wjp8 >> 2) + 2) << 4);
  int sl = wjp8 & 3;
  uint32_t* af00 = &Af[0][wkg][rgw][L0][sl];
  uint32_t* af01 = &Af[0][wkg][rgw][L1][sl];
  uint32_t* af10 = &Af[1][wkg][rgw][L0][sl];
  uint32_t* af11 = &Af[1][wkg][rgw][L1][sl];
  const float2* gCp = cxy + (size_t)wkg * (S >> 1) + 2 * wjp8;

  // ---- staging role: one full 64-B column (4 x uint4) per thread per step
  int scol = v;                      // 0..255
  const uint16_t* gB0 = tgt2 + (size_t)(wkg * NT) * TSTRIDE + (size_t)scol * 32;

  f32x4 acc0[4] = {};
  f32x4 acc1[4] = {};
  float rs = 0.f;

  // ---- prologue: stage tile 0 (B + w) into buffer 0; preload c(tile 1)
  {
    uint4 q0 = *(const uint4*)(gB0);
    uint4 q1 = *(const uint4*)(gB0 + 8);
    uint4 q2 = *(const uint4*)(gB0 + 16);
    uint4 q3 = *(const uint4*)(gB0 + 24);
    *(uint4*)&Bt[0][wkg][scol][0]  = q0;
    *(uint4*)&Bt[0][wkg][scol][8]  = q1;
    *(uint4*)&Bt[0][wkg][scol][16] = q2;
    *(uint4*)&Bt[0][wkg][scol][24] = q3;
    float4 ca = *(const float4*)(gCp);
    float4 cb = *(const float4*)(gCp + 16);
    float wA = wfun(hx_w, hy_w, ca.x, ca.y);
    float wB = wfun(hx_w, hy_w, ca.z, ca.w);
    float wC = wfun(hx_w, hy_w, cb.x, cb.y);
    float wD = wfun(hx_w, hy_w, cb.z, cb.w);
    rs += (wA + wB) + (wC + wD);
    *af00 = cvt_pk_bf16(wA, wB);
    *af01 = cvt_pk_bf16(wC, wD);
  }
  float4 ccur0 = *(const float4*)(gCp + 32);       // c for tile 1
  float4 ccur1 = *(const float4*)(gCp + 48);
  __syncthreads();

  for (int ts = 0; ts < NT; ++ts) {
    int cur = ts & 1, nxt = cur ^ 1;
    int tn = (ts + 1 < NT) ? ts + 1 : 0;   // next tile (wrap harmless)
    int tf = (ts + 2 < NT) ? ts + 2 : 0;   // c two ahead

    // issue next-tile B loads + c(ts+2) (latency hidden by compute)
    const uint16_t* bp = gB0 + (size_t)tn * TSTRIDE;
    uint4 q0 = *(const uint4*)(bp);
    uint4 q1 = *(const uint4*)(bp + 8);
    uint4 q2 = *(const uint4*)(bp + 16);
    uint4 q3 = *(const uint4*)(bp + 24);
    float4 cf0 = *(const float4*)(gCp + (size_t)tf * 32);
    float4 cf1 = *(const float4*)(gCp + (size_t)tf * 32 + 16);

    // read both A-frags + 4 B-frags; 8 MFMA
    short8 a0 = *(const short8*)&Af[cur][kg][0][lane][0];
    short8 a1 = *(const short8*)&Af[cur][kg][1][lane][0];
    const uint16_t* br = &Bt[cur][kg][n0][kch * 8];
    short8 b0 = *(const short8*)(br);
    short8 b1 = *(const short8*)(br + 16 * COLS);
    short8 b2 = *(const short8*)(br + 32 * COLS);
    short8 b3 = *(const short8*)(br + 48 * COLS);

    acc0[0] = __builtin_amdgcn_mfma_f32_16x16x32_bf16(a0, b0, acc0[0], 0, 0, 0);
    acc0[1] = __builtin_amdgcn_mfma_f32_16x16x32_bf16(a0, b1, acc0[1], 0, 0, 0);
    acc0[2] = __builtin_amdgcn_mfma_f32_16x16x32_bf16(a0, b2, acc0[2], 0, 0, 0);
    acc0[3] = __builtin_amdgcn_mfma_f32_16x16x32_bf16(a0, b3, acc0[3], 0, 0, 0);
    acc1[0] = __builtin_amdgcn_mfma_f32_16x16x32_bf16(a1, b0, acc1[0], 0, 0, 0);
    acc1[1] = __builtin_amdgcn_mfma_f32_16x16x32_bf16(a1, b1, acc1[1], 0, 0, 0);
    acc1[2] = __builtin_amdgcn_mfma_f32_16x16x32_bf16(a1, b2, acc1[2], 0, 0, 0);
    acc1[3] = __builtin_amdgcn_mfma_f32_16x16x32_bf16(a1, b3, acc1[3], 0, 0, 0);

    // w-gen for tile ts+1 (rs gated off on the wrapped last step)
    float wA = wfun(hx_w, hy_w, ccur0.x, ccur0.y);
    float wB = wfun(hx_w, hy_w, ccur0.z, ccur0.w);
    float wC = wfun(hx_w, hy_w, ccur1.x, ccur1.y);
    float wD = wfun(hx_w, hy_w, ccur1.z, ccur1.w);
    float g = (ts + 1 < NT) ? 1.f : 0.f;
    rs = fmaf(g, (wA + wB) + (wC + wD), rs);
    uint32_t pkA = cvt_pk_bf16(wA, wB);
    uint32_t pkB = cvt_pk_bf16(wC, wD);
    *(nxt ? af10 : af00) = pkA;
    *(nxt ? af11 : af01) = pkB;

    // write staged B to the other buffer (safe: nxt's reads done last step)
    *(uint4*)&Bt[nxt][wkg][scol][0]  = q0;
    *(uint4*)&Bt[nxt][wkg][scol][8]  = q1;
    *(uint4*)&Bt[nxt][wkg][scol][16] = q2;
    *(uint4*)&Bt[nxt][wkg][scol][24] = q3;

    ccur0 = cf0;
    ccur1 = cf1;
    __syncthreads();
  }

  // ---- rowsum: per-thread (kg,row,wjp8) partials -> LDS reduce
  rs_l[wkg][wr][wjp8] = rs;

  // kg=1 publishes its partial acc
  int rbase = (lane >> 4) * 4;
  if (kg == 1) {
    #pragma unroll
    for (int r = 0; r < 4; ++r) {
      comb[rbase + r][n0]      = acc0[0][r];
      comb[rbase + r][n0 + 16] = acc0[1][r];
      comb[rbase + r][n0 + 32] = acc0[2][r];
      comb[rbase + r][n0 + 48] = acc0[3][r];
      comb[16 + rbase + r][n0]      = acc1[0][r];
      comb[16 + rbase + r][n0 + 16] = acc1[1][r];
      comb[16 + rbase + r][n0 + 32] = acc1[2][r];
      comb[16 + rbase + r][n0 + 48] = acc1[3][r];
    }
  }
  __syncthreads();
  if (t < 32) {
    float r = 0.f;
    #pragma unroll
    for (int jp = 0; jp < 8; ++jp) r += rs_l[0][t][jp] + rs_l[1][t][jp];
    float fv = validf[i0 + t];
    scale_s[t] = (fv > 0.f) ? 1.0f / fmaxf(r, 1e-30f) : 0.f;
  }
  __syncthreads();
  if (kg == 0) {
    #pragma unroll
    for (int r = 0; r < 4; ++r) {
      int row0 = rbase + r;
      float s0 = scale_s[row0];
      size_t base0 = (size_t)(i0 + row0) * A;
      out[base0 + n0]      = (acc0[0][r] + comb[row0][n0]) * s0;
      out[base0 + n0 + 16] = (acc0[1][r] + comb[row0][n0 + 16]) * s0;
      out[base0 + n0 + 32] = (acc0[2][r] + comb[row0][n0 + 32]) * s0;
      out[base0 + n0 + 48] = (acc0[3][r] + comb[row0][n0 + 48]) * s0;
      int row1 = 16 + rbase + r;
      float s1 = scale_s[row1];
      size_t base1 = (size_t)(i0 + row1) * A;
      out[base1 + n0]      = (acc1[0][r] + comb[row1][n0]) * s1;
      out[base1 + n0 + 16] = (acc1[1][r] + comb[row1][n0 + 16]) * s1;
      out[base1 + n0 + 32] = (acc1[2][r] + comb[row1][n0 + 32]) * s1;
      out[base1 + n0 + 48] = (acc1[3][r] + comb[row1][n0 + 48]) * s1;
    }
  }
}

extern "C" void kernel_launch(void* const* d_in, const int* in_sizes, int n_in,
                              void* d_out, int out_size, void* d_ws, size_t ws_size,
                              hipStream_t stream) {
  // inputs: 0 batch[S,F] 1 xywh[S,4] 2 OW 3 OH 4 actor_weights[S] 5 avg_pos[S,2]
  //         6 W_h[F,2] 7 b_h[2] 8 W_g[F,A] 9 b_g[A] 10 num_person
  const float* batch = (const float*)d_in[0];
  const float* xywh  = (const float*)d_in[1];
  const float* W_h   = (const float*)d_in[6];
  const float* b_h   = (const float*)d_in[7];
  const float* W_g   = (const float*)d_in[8];
  const float* b_g   = (const float*)d_in[9];
  int S = in_sizes[4];
  int F = in_sizes[0] / S;
  int A = in_sizes[9];

  float* out    = (float*)d_out;
  float* out_tw = out;                        // [S,A]
  float* out_hp = out + (size_t)S * A;        // [S,2]

  // workspace: tgt2 bf16 [S/32][A][32], WgT bf16 [A][F], hx/hy/validf, cxy
  uint16_t* tgt2 = (uint16_t*)d_ws;
  uint16_t* WgT  = tgt2 + (size_t)A * S;
  float* hxv = (float*)(WgT + (size_t)A * F);
  float* hyv = hxv + S;
  float* vfv = hyv + S;
  float2* cxyv = (float2*)(vfv + S);

  k_head<<<dim3((S + 3) / 4), 256, 0, stream>>>(batch, xywh, W_h, b_h,
                                                out_hp, hxv, hyv, vfv, cxyv, S, F);
  k_prep_w<<<dim3((A * F / 8 + 255) / 256), 256, 0, stream>>>(W_g, WgT, F, A);
  k_targets_mfma<<<dim3(S / 32), 256, 0, stream>>>(batch, WgT, b_g, tgt2, S, F, A);
  k_gather_v19<<<dim3(S / 32), 512, 0, stream>>>(tgt2, cxyv, hxv, hyv, vfv,
                                                 out_tw, S, A);
}

// Round 20
// 152.462 us; speedup vs baseline: 1.1240x; 1.0552x over previous
//
#include <hip/hip_runtime.h>
#include <math.h>
#include <stdint.h>

typedef __attribute__((ext_vector_type(8))) short short8;
typedef __attribute__((ext_vector_type(4))) float f32x4;

__device__ __forceinline__ uint32_t cvt_pk_bf16(float lo, float hi) {
  uint32_t r;
  asm("v_cvt_pk_bf16_f32 %0, %1, %2" : "=v"(r) : "v"(lo), "v"(hi));
  return r;
}

// inverse-distance weight; invalid j has cx=cy=1e30 -> d2 overflows to inf
// -> rcp(inf)=0, so invalid columns contribute exactly 0.
__device__ __forceinline__ float wfun(float hx, float hy, float cx, float cy) {
  float dx = hx - cx, dy = hy - cy;
  float d = __builtin_amdgcn_sqrtf(fmaf(dx, dx, dy * dy));
  return __builtin_amdgcn_rcpf(d + 1e-4f);
}

// ---------------------------------------------------------------------------
// Kernel 1: hp = tanh(batch@W_h + b_h); hx,hy,validf,cxy per row. (verified)
__global__ __launch_bounds__(256) void k_head(
    const float* __restrict__ batch, const float* __restrict__ xywh,
    const float* __restrict__ W_h, const float* __restrict__ b_h,
    float* __restrict__ hp_out, float* __restrict__ hx, float* __restrict__ hy,
    float* __restrict__ validf, float2* __restrict__ cxy, int S, int F) {
  int wid = threadIdx.x >> 6;
  int lane = threadIdx.x & 63;
  int row = blockIdx.x * 4 + wid;
  if (row >= S) return;
  const float4* brow = (const float4*)(batch + (size_t)row * F);
  const float4* wh4 = (const float4*)W_h;  // W_h is [F,2] row-major
  int nf4 = F >> 2;
  float acc0 = 0.f, acc1 = 0.f;
  for (int k4 = lane; k4 < nf4; k4 += 64) {
    float4 b = brow[k4];
    float4 wa = wh4[2 * k4];
    float4 wb = wh4[2 * k4 + 1];
    acc0 += b.x * wa.x + b.y * wa.z + b.z * wb.x + b.w * wb.z;
    acc1 += b.x * wa.y + b.y * wa.w + b.z * wb.y + b.w * wb.w;
  }
  #pragma unroll
  for (int off = 32; off; off >>= 1) {
    acc0 += __shfl_xor(acc0, off, 64);
    acc1 += __shfl_xor(acc1, off, 64);
  }
  if (lane == 0) {
    float hp0 = tanhf(acc0 + b_h[0]);
    float hp1 = tanhf(acc1 + b_h[1]);
    float4 xy = ((const float4*)xywh)[row];
    hp_out[2 * row] = hp0;
    hp_out[2 * row + 1] = hp1;
    hx[row] = hp0 * xy.z * 4.0f + xy.x;  // SIGMA_X = 4
    hy[row] = hp1 * xy.w * 1.0f + xy.y;  // SIGMA_Y = 1
    bool v = (xy.x + xy.y + xy.z + xy.w >= 1e-8f);
    validf[row] = v ? 1.0f : 0.0f;
    cxy[row] = v ? make_float2(xy.x, xy.y) : make_float2(1e30f, 1e30f);
  }
}

// ---------------------------------------------------------------------------
// Kernel 1b: WgT[a][k] = bf16(Wg[k][a])  (verified)
__global__ __launch_bounds__(256) void k_prep_w(
    const float* __restrict__ Wg, uint16_t* __restrict__ WgT, int F, int A) {
  int idx = blockIdx.x * 256 + threadIdx.x;
  int a = idx % A;
  int k0 = (idx / A) * 8;
  if (k0 >= F) return;
  float f[8];
  #pragma unroll
  for (int e = 0; e < 8; ++e) f[e] = Wg[(size_t)(k0 + e) * A + a];
  uint4 v;
  v.x = cvt_pk_bf16(f[0], f[1]);
  v.y = cvt_pk_bf16(f[2], f[3]);
  v.z = cvt_pk_bf16(f[4], f[5]);
  v.w = cvt_pk_bf16(f[6], f[7]);
  *(uint4*)(WgT + (size_t)a * F + k0) = v;
}

// ---------------------------------------------------------------------------
// Kernel 2: targets via bf16 MFMA; tiled output tgt2[jb][a][jj].
// Verified body; occupancy fix: BM=16, grid S/16 = 512 blocks = 2 blocks/CU
// = 2 waves/SIMD (was 1 — latency-bound). 4 waves = 4 wn (64 cols, nf=4).
// Stores land in the (bx&1) 16-row half of tgt2 tile jb = bx>>1.
__global__ __launch_bounds__(256) void k_targets_mfma(
    const float* __restrict__ batch, const uint16_t* __restrict__ WgT,
    const float* __restrict__ bg, uint16_t* __restrict__ tgt2,
    int S, int F, int A) {
  int t = threadIdx.x;
  int lane = t & 63, wn = t >> 6;        // 4 waves = 4 col groups
  int i0 = blockIdx.x * 16;
  int row = i0 + (lane & 15);
  int kch = lane >> 4;
  const float* ab = batch + (size_t)row * F + kch * 8;
  int ncol0 = wn * 64 + (lane & 15);
  const uint16_t* bb = WgT + (size_t)ncol0 * F + kch * 8;

  f32x4 acc[4] = {};
  float4 a0 = *(const float4*)(ab);
  float4 a1 = *(const float4*)(ab + 4);
  short8 bf[4];
  #pragma unroll
  for (int nf = 0; nf < 4; ++nf)
    bf[nf] = *(const short8*)(bb + (size_t)nf * 16 * F);

  for (int k0 = 0; k0 < F; k0 += 32) {
    int kn = (k0 + 32 < F) ? k0 + 32 : 0;  // wrap prefetch (harmless)
    float4 na0 = *(const float4*)(ab + kn);
    float4 na1 = *(const float4*)(ab + kn + 4);
    short8 nbf[4];
    #pragma unroll
    for (int nf = 0; nf < 4; ++nf)
      nbf[nf] = *(const short8*)(bb + kn + (size_t)nf * 16 * F);
    union { short8 s; uint32_t u[4]; } af;
    af.u[0] = cvt_pk_bf16(a0.x, a0.y);
    af.u[1] = cvt_pk_bf16(a0.z, a0.w);
    af.u[2] = cvt_pk_bf16(a1.x, a1.y);
    af.u[3] = cvt_pk_bf16(a1.z, a1.w);
    #pragma unroll
    for (int nf = 0; nf < 4; ++nf)
      acc[nf] = __builtin_amdgcn_mfma_f32_16x16x32_bf16(af.s, bf[nf], acc[nf], 0, 0, 0);
    a0 = na0; a1 = na1;
    #pragma unroll
    for (int nf = 0; nf < 4; ++nf) bf[nf] = nbf[nf];
  }

  int jb = blockIdx.x >> 1;
  int half = (blockIdx.x & 1) * 16;
  int rloc = half + (lane >> 4) * 4;      // row within 32-row tile
  #pragma unroll
  for (int nf = 0; nf < 4; ++nf) {
    int col = ncol0 + nf * 16;
    float b = bg[col];
    float o0 = fmaxf(acc[nf][0] + b, 0.f);
    float o1 = fmaxf(acc[nf][1] + b, 0.f);
    float o2 = fmaxf(acc[nf][2] + b, 0.f);
    float o3 = fmaxf(acc[nf][3] + b, 0.f);
    uint2 pk;
    pk.x = cvt_pk_bf16(o0, o1);
    pk.y = cvt_pk_bf16(o2, o3);
    *(uint2*)(tgt2 + ((size_t)jb * A + col) * 32 + rloc) = pk;
  }
}

// ---------------------------------------------------------------------------
// Kernel 3: out = rownorm(W) @ targets. Round-16 verified kernel (102.5 us),
// byte-identical: 1024 thr = 2(kg) x 2(wm) x 4(wn); 1-barrier dbuf pipeline;
// dedup w-gen via Af (2 wfun/thread/step); reg-staged stride-40 Bt.
__global__ __launch_bounds__(1024, 4) void k_gather_v16(
    const uint16_t* __restrict__ tgt2, const float2* __restrict__ cxy,
    const float* __restrict__ hx, const float* __restrict__ hy,
    const float* __restrict__ validf, float* __restrict__ out, int S, int A) {
  __shared__ uint16_t Bt[2][2][256][40];   // [dbuf][kg][col][40hw]   80 KB
  __shared__ uint32_t Af[2][2][2][64][4];  // [dbuf][kg][wm][lane][s]  8 KB
  __shared__ float comb[32][260];          // kg=1 partial acc        33.3 KB
  __shared__ float rs_l[2][32][16];        // [kg][row][jp]            4 KB
  __shared__ float scale_s[32];

  int t = threadIdx.x;
  int lane = t & 63, wid = t >> 6;
  int kg = wid >> 3;                 // 0..1 (j-half)
  int sub = wid & 7;
  int wm = sub >> 2, wn = sub & 3;   // 2M x 4N
  int i0 = blockIdx.x * 32;
  int kch = lane >> 4;
  int n0 = wn * 64 + (lane & 15);    // col 0..255
  int NT = (S >> 1) / 32;            // 128 tiles per K-group
  const size_t TSTRIDE = (size_t)A * 32;
  const int COLS = 40;

  // ---- writer role (all 1024 threads): (row wr, j-pair wjp) of kg's tile
  int u = t & 511;
  int wr = u & 31;                   // 0..31
  int wjp = u >> 5;                  // 0..15
  float hx_w = hx[i0 + wr], hy_w = hy[i0 + wr];
  uint32_t* afw0 = &Af[0][kg][wr >> 4][(wr & 15) | ((wjp >> 2) << 4)][wjp & 3];
  uint32_t* afw1 = &Af[1][kg][wr >> 4][(wr & 15) | ((wjp >> 2) << 4)][wjp & 3];
  const float2* gC = cxy + (size_t)kg * (S >> 1) + 2 * wjp;  // + tile*32

  // ---- staging role: 32 B (2 x uint4) of kg's tile per step
  int scol = u >> 1;                 // 0..255
  int skw = u & 1;                   // 0..1 (32-B half of the 64-B column)
  const uint16_t* gB0 = tgt2 + (size_t)(kg * NT) * TSTRIDE
                        + (size_t)scol * 32 + skw * 16;

  f32x4 acc[4] = {};
  float rs = 0.f;

  // ---- prologue: w(tile0) + B(tile0) into buffer 0; preload c(tile1)
  {
    float4 c0 = *(const float4*)(gC);
    float wA = wfun(hx_w, hy_w, c0.x, c0.y);
    float wB = wfun(hx_w, hy_w, c0.z, c0.w);
    rs += wA + wB;
    *afw0 = cvt_pk_bf16(wA, wB);
    uint4 ga = *(const uint4*)(gB0);
    uint4 gb = *(const uint4*)(gB0 + 8);
    *(uint4*)&Bt[0][kg][scol][skw * 16] = ga;
    *(uint4*)&Bt[0][kg][scol][skw * 16 + 8] = gb;
  }
  float4 ccur = *(const float4*)(gC + 32);   // c for tile 1
  __syncthreads();

  for (int ts = 0; ts < NT; ++ts) {
    int nxt = (ts & 1) ^ 1;
    int tn = (ts + 1 < NT) ? ts + 1 : 0;     // next tile (wrap harmless)
    int tf = (ts + 2 < NT) ? ts + 2 : 0;     // c two ahead

    // issue next-tile B loads + c(ts+2) load (latency hidden by compute)
    const uint16_t* bp = gB0 + (size_t)tn * TSTRIDE;
    uint4 ga = *(const uint4*)(bp);
    uint4 gb = *(const uint4*)(bp + 8);
    float4 cfut = *(const float4*)(gC + (size_t)tf * 32);

    // read A-frag + B-frags for current tile
    const uint32_t* afp = &Af[ts & 1][kg][wm][lane][0];
    short8 afr = *(const short8*)afp;
    const uint16_t* br = &Bt[ts & 1][kg][n0][kch * 8];
    short8 b0 = *(const short8*)(br);
    short8 b1 = *(const short8*)(br + 16 * COLS);
    short8 b2 = *(const short8*)(br + 32 * COLS);
    short8 b3 = *(const short8*)(br + 48 * COLS);

    acc[0] = __builtin_amdgcn_mfma_f32_16x16x32_bf16(afr, b0, acc[0], 0, 0, 0);
    acc[1] = __builtin_amdgcn_mfma_f32_16x16x32_bf16(afr, b1, acc[1], 0, 0, 0);
    acc[2] = __builtin_amdgcn_mfma_f32_16x16x32_bf16(afr, b2, acc[2], 0, 0, 0);
    acc[3] = __builtin_amdgcn_mfma_f32_16x16x32_bf16(afr, b3, acc[3], 0, 0, 0);

    // w-gen for tile ts+1 (rs gated off on the wrapped last step)
    float wA = wfun(hx_w, hy_w, ccur.x, ccur.y);
    float wB = wfun(hx_w, hy_w, ccur.z, ccur.w);
    float g = (ts + 1 < NT) ? 1.f : 0.f;
    rs = fmaf(g, wA + wB, rs);
    uint32_t pk = cvt_pk_bf16(wA, wB);
    uint32_t* afw = nxt ? afw1 : afw0;
    *afw = pk;

    // write staged B to the other buffer
    *(uint4*)&Bt[nxt][kg][scol][skw * 16] = ga;
    *(uint4*)&Bt[nxt][kg][scol][skw * 16 + 8] = gb;
    ccur = cfut;
    __syncthreads();
  }

  // ---- rowsum: per-thread (kg,row,jp) partials -> LDS reduce
  rs_l[kg][wr][wjp] = rs;

  // kg=1 publishes its partial acc
  if (kg == 1) {
    int mre = wm * 16 + (lane >> 4) * 4;
    #pragma unroll
    for (int r = 0; r < 4; ++r) {
      comb[mre + r][n0]      = acc[0][r];
      comb[mre + r][n0 + 16] = acc[1][r];
      comb[mre + r][n0 + 32] = acc[2][r];
      comb[mre + r][n0 + 48] = acc[3][r];
    }
  }
  __syncthreads();
  if (t < 32) {
    float r = 0.f;
    #pragma unroll
    for (int jp = 0; jp < 16; ++jp) r += rs_l[0][t][jp] + rs_l[1][t][jp];
    float v = validf[i0 + t];
    scale_s[t] = (v > 0.f) ? 1.0f / fmaxf(r, 1e-30f) : 0.f;
  }
  __syncthreads();
  if (kg == 0) {
    int mre = wm * 16 + (lane >> 4) * 4;
    #pragma unroll
    for (int r = 0; r < 4; ++r) {
      float s = scale_s[mre + r];
      size_t base = (size_t)(i0 + mre + r) * A;
      out[base + n0]      = (acc[0][r] + comb[mre + r][n0]) * s;
      out[base + n0 + 16] = (acc[1][r] + comb[mre + r][n0 + 16]) * s;
      out[base + n0 + 32] = (acc[2][r] + comb[mre + r][n0 + 32]) * s;
      out[base + n0 + 48] = (acc[3][r] + comb[mre + r][n0 + 48]) * s;
    }
  }
}

extern "C" void kernel_launch(void* const* d_in, const int* in_sizes, int n_in,
                              void* d_out, int out_size, void* d_ws, size_t ws_size,
                              hipStream_t stream) {
  // inputs: 0 batch[S,F] 1 xywh[S,4] 2 OW 3 OH 4 actor_weights[S] 5 avg_pos[S,2]
  //         6 W_h[F,2] 7 b_h[2] 8 W_g[F,A] 9 b_g[A] 10 num_person
  const float* batch = (const float*)d_in[0];
  const float* xywh  = (const float*)d_in[1];
  const float* W_h   = (const float*)d_in[6];
  const float* b_h   = (const float*)d_in[7];
  const float* W_g   = (const float*)d_in[8];
  const float* b_g   = (const float*)d_in[9];
  int S = in_sizes[4];
  int F = in_sizes[0] / S;
  int A = in_sizes[9];

  float* out    = (float*)d_out;
  float* out_tw = out;                        // [S,A]
  float* out_hp = out + (size_t)S * A;        // [S,2]

  // workspace: tgt2 bf16 [S/32][A][32], WgT bf16 [A][F], hx/hy/validf, cxy
  uint16_t* tgt2 = (uint16_t*)d_ws;
  uint16_t* WgT  = tgt2 + (size_t)A * S;
  float* hxv = (float*)(WgT + (size_t)A * F);
  float* hyv = hxv + S;
  float* vfv = hyv + S;
  float2* cxyv = (float2*)(vfv + S);

  k_head<<<dim3((S + 3) / 4), 256, 0, stream>>>(batch, xywh, W_h, b_h,
                                                out_hp, hxv, hyv, vfv, cxyv, S, F);
  k_prep_w<<<dim3((A * F / 8 + 255) / 256), 256, 0, stream>>>(W_g, WgT, F, A);
  k_targets_mfma<<<dim3(S / 16), 256, 0, stream>>>(batch, WgT, b_g, tgt2, S, F, A);
  k_gather_v16<<<dim3(S / 32), 1024, 0, stream>>>(tgt2, cxyv, hxv, hyv, vfv,
                                                  out_tw, S, A);
}

// Round 21
// 142.944 us; speedup vs baseline: 1.1988x; 1.0666x over previous
//
#include <hip/hip_runtime.h>
#include <math.h>
#include <stdint.h>

typedef __attribute__((ext_vector_type(8))) short short8;
typedef __attribute__((ext_vector_type(4))) float f32x4;

__device__ __forceinline__ uint32_t cvt_pk_bf16(float lo, float hi) {
  uint32_t r;
  asm("v_cvt_pk_bf16_f32 %0, %1, %2" : "=v"(r) : "v"(lo), "v"(hi));
  return r;
}

// inverse-distance weight; invalid j has cx=cy=1e30 -> d2 overflows to inf
// -> rcp(inf)=0, so invalid columns contribute exactly 0.
__device__ __forceinline__ float wfun(float hx, float hy, float cx, float cy) {
  float dx = hx - cx, dy = hy - cy;
  float d = __builtin_amdgcn_sqrtf(fmaf(dx, dx, dy * dy));
  return __builtin_amdgcn_rcpf(d + 1e-4f);
}

// ---------------------------------------------------------------------------
// Kernel 1: WgT[a][k] = bf16(Wg[k][a])  (verified)
__global__ __launch_bounds__(256) void k_prep_w(
    const float* __restrict__ Wg, uint16_t* __restrict__ WgT, int F, int A) {
  int idx = blockIdx.x * 256 + threadIdx.x;
  int a = idx % A;
  int k0 = (idx / A) * 8;
  if (k0 >= F) return;
  float f[8];
  #pragma unroll
  for (int e = 0; e < 8; ++e) f[e] = Wg[(size_t)(k0 + e) * A + a];
  uint4 v;
  v.x = cvt_pk_bf16(f[0], f[1]);
  v.y = cvt_pk_bf16(f[2], f[3]);
  v.z = cvt_pk_bf16(f[4], f[5]);
  v.w = cvt_pk_bf16(f[6], f[7]);
  *(uint4*)(WgT + (size_t)a * F + k0) = v;
}

// ---------------------------------------------------------------------------
// Kernel 2 (FUSED targets + head): round-16-verified k_targets_mfma body
// (BM=32, 4 waves = 2wm x 2wn, nf=8, 256 blocks) with the fp32 W_h side-dot
// folded into the wn==0 waves (wave-uniform branch; reuses the already-loaded
// fp32 a0/a1). Epilogue writes hp/hx/hy/validf/cxy — same math as k_head.
__global__ __launch_bounds__(256) void k_fused_tgt_head(
    const float* __restrict__ batch, const uint16_t* __restrict__ WgT,
    const float* __restrict__ bg, const float* __restrict__ W_h,
    const float* __restrict__ b_h, const float* __restrict__ xywh,
    uint16_t* __restrict__ tgt2, float* __restrict__ hp_out,
    float* __restrict__ hx, float* __restrict__ hy,
    float* __restrict__ validf, float2* __restrict__ cxy,
    int S, int F, int A) {
  int t = threadIdx.x;
  int lane = t & 63, wid = t >> 6;
  int wm = wid >> 1, wn = wid & 1;
  int i0 = blockIdx.x * 32;
  int row = i0 + wm * 16 + (lane & 15);
  int kch = lane >> 4;
  const float* ab = batch + (size_t)row * F + kch * 8;
  int ncol0 = wn * 128 + (lane & 15);
  const uint16_t* bb = WgT + (size_t)ncol0 * F + kch * 8;

  f32x4 acc[8] = {};
  float wh0 = 0.f, wh1 = 0.f;
  float4 a0 = *(const float4*)(ab);
  float4 a1 = *(const float4*)(ab + 4);
  short8 bf[8];
  #pragma unroll
  for (int nf = 0; nf < 8; ++nf)
    bf[nf] = *(const short8*)(bb + (size_t)nf * 16 * F);

  for (int k0 = 0; k0 < F; k0 += 32) {
    int kn = (k0 + 32 < F) ? k0 + 32 : 0;  // wrap prefetch (harmless)
    float4 na0 = *(const float4*)(ab + kn);
    float4 na1 = *(const float4*)(ab + kn + 4);
    short8 nbf[8];
    #pragma unroll
    for (int nf = 0; nf < 8; ++nf)
      nbf[nf] = *(const short8*)(bb + kn + (size_t)nf * 16 * F);

    if (wn == 0) {  // fp32 W_h side-dot on this lane's 8 k's (exact path)
      const float* whp = W_h + 2 * (k0 + kch * 8);
      float4 h0 = *(const float4*)(whp);
      float4 h1 = *(const float4*)(whp + 4);
      float4 h2 = *(const float4*)(whp + 8);
      float4 h3 = *(const float4*)(whp + 12);
      wh0 += a0.x*h0.x + a0.y*h0.z + a0.z*h1.x + a0.w*h1.z
           + a1.x*h2.x + a1.y*h2.z + a1.z*h3.x + a1.w*h3.z;
      wh1 += a0.x*h0.y + a0.y*h0.w + a0.z*h1.y + a0.w*h1.w
           + a1.x*h2.y + a1.y*h2.w + a1.z*h3.y + a1.w*h3.w;
    }

    union { short8 s; uint32_t u[4]; } af;
    af.u[0] = cvt_pk_bf16(a0.x, a0.y);
    af.u[1] = cvt_pk_bf16(a0.z, a0.w);
    af.u[2] = cvt_pk_bf16(a1.x, a1.y);
    af.u[3] = cvt_pk_bf16(a1.z, a1.w);
    #pragma unroll
    for (int nf = 0; nf < 8; ++nf)
      acc[nf] = __builtin_amdgcn_mfma_f32_16x16x32_bf16(af.s, bf[nf], acc[nf], 0, 0, 0);
    a0 = na0; a1 = na1;
    #pragma unroll
    for (int nf = 0; nf < 8; ++nf) bf[nf] = nbf[nf];
  }

  int jb = blockIdx.x;
  int rloc = wm * 16 + (lane >> 4) * 4;   // row within tile, mult of 4
  #pragma unroll
  for (int nf = 0; nf < 8; ++nf) {
    int col = ncol0 + nf * 16;
    float b = bg[col];
    float o0 = fmaxf(acc[nf][0] + b, 0.f);
    float o1 = fmaxf(acc[nf][1] + b, 0.f);
    float o2 = fmaxf(acc[nf][2] + b, 0.f);
    float o3 = fmaxf(acc[nf][3] + b, 0.f);
    uint2 pk;
    pk.x = cvt_pk_bf16(o0, o1);
    pk.y = cvt_pk_bf16(o2, o3);
    *(uint2*)(tgt2 + ((size_t)jb * A + col) * 32 + rloc) = pk;
  }

  // head epilogue: reduce over the 4 kch groups, write per-row values
  if (wn == 0) {
    wh0 += __shfl_xor(wh0, 16, 64);
    wh0 += __shfl_xor(wh0, 32, 64);
    wh1 += __shfl_xor(wh1, 16, 64);
    wh1 += __shfl_xor(wh1, 32, 64);
    if (lane < 16) {
      int r = i0 + wm * 16 + lane;
      float hp0 = tanhf(wh0 + b_h[0]);
      float hp1 = tanhf(wh1 + b_h[1]);
      float4 xy = ((const float4*)xywh)[r];
      hp_out[2 * r] = hp0;
      hp_out[2 * r + 1] = hp1;
      hx[r] = hp0 * xy.z * 4.0f + xy.x;  // SIGMA_X = 4
      hy[r] = hp1 * xy.w * 1.0f + xy.y;  // SIGMA_Y = 1
      bool v = (xy.x + xy.y + xy.z + xy.w >= 1e-8f);
      validf[r] = v ? 1.0f : 0.0f;
      cxy[r] = v ? make_float2(xy.x, xy.y) : make_float2(1e30f, 1e30f);
    }
  }
}

// ---------------------------------------------------------------------------
// Kernel 3: out = rownorm(W) @ targets. Round-16 verified kernel (102.5 us),
// byte-identical: 1024 thr = 2(kg) x 2(wm) x 4(wn); 1-barrier dbuf pipeline;
// dedup w-gen via Af (2 wfun/thread/step); reg-staged stride-40 Bt.
__global__ __launch_bounds__(1024, 4) void k_gather_v16(
    const uint16_t* __restrict__ tgt2, const float2* __restrict__ cxy,
    const float* __restrict__ hx, const float* __restrict__ hy,
    const float* __restrict__ validf, float* __restrict__ out, int S, int A) {
  __shared__ uint16_t Bt[2][2][256][40];   // [dbuf][kg][col][40hw]   80 KB
  __shared__ uint32_t Af[2][2][2][64][4];  // [dbuf][kg][wm][lane][s]  8 KB
  __shared__ float comb[32][260];          // kg=1 partial acc        33.3 KB
  __shared__ float rs_l[2][32][16];        // [kg][row][jp]            4 KB
  __shared__ float scale_s[32];

  int t = threadIdx.x;
  int lane = t & 63, wid = t >> 6;
  int kg = wid >> 3;                 // 0..1 (j-half)
  int sub = wid & 7;
  int wm = sub >> 2, wn = sub & 3;   // 2M x 4N
  int i0 = blockIdx.x * 32;
  int kch = lane >> 4;
  int n0 = wn * 64 + (lane & 15);    // col 0..255
  int NT = (S >> 1) / 32;            // 128 tiles per K-group
  const size_t TSTRIDE = (size_t)A * 32;
  const int COLS = 40;

  // ---- writer role (all 1024 threads): (row wr, j-pair wjp) of kg's tile
  int u = t & 511;
  int wr = u & 31;                   // 0..31
  int wjp = u >> 5;                  // 0..15
  float hx_w = hx[i0 + wr], hy_w = hy[i0 + wr];
  uint32_t* afw0 = &Af[0][kg][wr >> 4][(wr & 15) | ((wjp >> 2) << 4)][wjp & 3];
  uint32_t* afw1 = &Af[1][kg][wr >> 4][(wr & 15) | ((wjp >> 2) << 4)][wjp & 3];
  const float2* gC = cxy + (size_t)kg * (S >> 1) + 2 * wjp;  // + tile*32

  // ---- staging role: 32 B (2 x uint4) of kg's tile per step
  int scol = u >> 1;                 // 0..255
  int skw = u & 1;                   // 0..1 (32-B half of the 64-B column)
  const uint16_t* gB0 = tgt2 + (size_t)(kg * NT) * TSTRIDE
                        + (size_t)scol * 32 + skw * 16;

  f32x4 acc[4] = {};
  float rs = 0.f;

  // ---- prologue: w(tile0) + B(tile0) into buffer 0; preload c(tile1)
  {
    float4 c0 = *(const float4*)(gC);
    float wA = wfun(hx_w, hy_w, c0.x, c0.y);
    float wB = wfun(hx_w, hy_w, c0.z, c0.w);
    rs += wA + wB;
    *afw0 = cvt_pk_bf16(wA, wB);
    uint4 ga = *(const uint4*)(gB0);
    uint4 gb = *(const uint4*)(gB0 + 8);
    *(uint4*)&Bt[0][kg][scol][skw * 16] = ga;
    *(uint4*)&Bt[0][kg][scol][skw * 16 + 8] = gb;
  }
  float4 ccur = *(const float4*)(gC + 32);   // c for tile 1
  __syncthreads();

  for (int ts = 0; ts < NT; ++ts) {
    int nxt = (ts & 1) ^ 1;
    int tn = (ts + 1 < NT) ? ts + 1 : 0;     // next tile (wrap harmless)
    int tf = (ts + 2 < NT) ? ts + 2 : 0;     // c two ahead

    // issue next-tile B loads + c(ts+2) load (latency hidden by compute)
    const uint16_t* bp = gB0 + (size_t)tn * TSTRIDE;
    uint4 ga = *(const uint4*)(bp);
    uint4 gb = *(const uint4*)(bp + 8);
    float4 cfut = *(const float4*)(gC + (size_t)tf * 32);

    // read A-frag + B-frags for current tile
    const uint32_t* afp = &Af[ts & 1][kg][wm][lane][0];
    short8 afr = *(const short8*)afp;
    const uint16_t* br = &Bt[ts & 1][kg][n0][kch * 8];
    short8 b0 = *(const short8*)(br);
    short8 b1 = *(const short8*)(br + 16 * COLS);
    short8 b2 = *(const short8*)(br + 32 * COLS);
    short8 b3 = *(const short8*)(br + 48 * COLS);

    acc[0] = __builtin_amdgcn_mfma_f32_16x16x32_bf16(afr, b0, acc[0], 0, 0, 0);
    acc[1] = __builtin_amdgcn_mfma_f32_16x16x32_bf16(afr, b1, acc[1], 0, 0, 0);
    acc[2] = __builtin_amdgcn_mfma_f32_16x16x32_bf16(afr, b2, acc[2], 0, 0, 0);
    acc[3] = __builtin_amdgcn_mfma_f32_16x16x32_bf16(afr, b3, acc[3], 0, 0, 0);

    // w-gen for tile ts+1 (rs gated off on the wrapped last step)
    float wA = wfun(hx_w, hy_w, ccur.x, ccur.y);
    float wB = wfun(hx_w, hy_w, ccur.z, ccur.w);
    float g = (ts + 1 < NT) ? 1.f : 0.f;
    rs = fmaf(g, wA + wB, rs);
    uint32_t pk = cvt_pk_bf16(wA, wB);
    uint32_t* afw = nxt ? afw1 : afw0;
    *afw = pk;

    // write staged B to the other buffer
    *(uint4*)&Bt[nxt][kg][scol][skw * 16] = ga;
    *(uint4*)&Bt[nxt][kg][scol][skw * 16 + 8] = gb;
    ccur = cfut;
    __syncthreads();
  }

  // ---- rowsum: per-thread (kg,row,jp) partials -> LDS reduce
  rs_l[kg][wr][wjp] = rs;

  // kg=1 publishes its partial acc
  if (kg == 1) {
    int mre = wm * 16 + (lane >> 4) * 4;
    #pragma unroll
    for (int r = 0; r < 4; ++r) {
      comb[mre + r][n0]      = acc[0][r];
      comb[mre + r][n0 + 16] = acc[1][r];
      comb[mre + r][n0 + 32] = acc[2][r];
      comb[mre + r][n0 + 48] = acc[3][r];
    }
  }
  __syncthreads();
  if (t < 32) {
    float r = 0.f;
    #pragma unroll
    for (int jp = 0; jp < 16; ++jp) r += rs_l[0][t][jp] + rs_l[1][t][jp];
    float v = validf[i0 + t];
    scale_s[t] = (v > 0.f) ? 1.0f / fmaxf(r, 1e-30f) : 0.f;
  }
  __syncthreads();
  if (kg == 0) {
    int mre = wm * 16 + (lane >> 4) * 4;
    #pragma unroll
    for (int r = 0; r < 4; ++r) {
      float s = scale_s[mre + r];
      size_t base = (size_t)(i0 + mre + r) * A;
      out[base + n0]      = (acc[0][r] + comb[mre + r][n0]) * s;
      out[base + n0 + 16] = (acc[1][r] + comb[mre + r][n0 + 16]) * s;
      out[base + n0 + 32] = (acc[2][r] + comb[mre + r][n0 + 32]) * s;
      out[base + n0 + 48] = (acc[3][r] + comb[mre + r][n0 + 48]) * s;
    }
  }
}

extern "C" void kernel_launch(void* const* d_in, const int* in_sizes, int n_in,
                              void* d_out, int out_size, void* d_ws, size_t ws_size,
                              hipStream_t stream) {
  // inputs: 0 batch[S,F] 1 xywh[S,4] 2 OW 3 OH 4 actor_weights[S] 5 avg_pos[S,2]
  //         6 W_h[F,2] 7 b_h[2] 8 W_g[F,A] 9 b_g[A] 10 num_person
  const float* batch = (const float*)d_in[0];
  const float* xywh  = (const float*)d_in[1];
  const float* W_h   = (const float*)d_in[6];
  const float* b_h   = (const float*)d_in[7];
  const float* W_g   = (const float*)d_in[8];
  const float* b_g   = (const float*)d_in[9];
  int S = in_sizes[4];
  int F = in_sizes[0] / S;
  int A = in_sizes[9];

  float* out    = (float*)d_out;
  float* out_tw = out;                        // [S,A]
  float* out_hp = out + (size_t)S * A;        // [S,2]

  // workspace: tgt2 bf16 [S/32][A][32], WgT bf16 [A][F], hx/hy/validf, cxy
  uint16_t* tgt2 = (uint16_t*)d_ws;
  uint16_t* WgT  = tgt2 + (size_t)A * S;
  float* hxv = (float*)(WgT + (size_t)A * F);
  float* hyv = hxv + S;
  float* vfv = hyv + S;
  float2* cxyv = (float2*)(vfv + S);

  k_prep_w<<<dim3((A * F / 8 + 255) / 256), 256, 0, stream>>>(W_g, WgT, F, A);
  k_fused_tgt_head<<<dim3(S / 32), 256, 0, stream>>>(batch, WgT, b_g, W_h, b_h,
                                                     xywh, tgt2, out_hp, hxv,
                                                     hyv, vfv, cxyv, S, F, A);
  k_gather_v16<<<dim3(S / 32), 1024, 0, stream>>>(tgt2, cxyv, hxv, hyv, vfv,
                                                  out_tw, S, A);
}